// Round 5
// baseline (243.523 us; speedup 1.0000x reference)
//
#include <hip/hip_runtime.h>
#include <math.h>

#define B_DIM 256
#define T_DIM 8192
#define BLOCK 256
#define GRID  1024                      // 4 blocks/CU
#define NSLOT 256
#define ROWS_TOT (B_DIM * T_DIM)        // 2,097,152 rows
#define NPAIR (ROWS_TOT / 2)            // 1,048,576 row-pairs
#define NT    (GRID * BLOCK)            // 262,144 threads
#define NITER (NPAIR / NT)              // 4 iterations (exact, no tail)
#define NF4   (ROWS_TOT * 3)

// Streaming form: lane owns 2 consecutive rows (6 f4) per iteration.
//  - ALL terms lane-local: vel/acc via 6 extra contiguous f4 (rows t+2,t+3),
//    phase rows via 3+2 float2. No LDS, no barriers, no shuffles, no div3,
//    no divergent sentinels inside the loop. One base + imm offsets per array.
//  - tail (t==8190 pair) masks vel(row1)/acc/coher(r1,r2); E/e reloads own data.
// ws layout: NSLOT x 8 doubles: 0:sse+12*nll 1:coher_sum 2:coher_cnt 3:pen2 4:velsq 5:accsq

__device__ __forceinline__ float pen_term(float s) {
    float d = fmaxf(sqrtf(s) - 10.0f, 0.0f);
    return d * d;
}
__device__ __forceinline__ void argmax3(float l0, float l1, float l2, int &p, float &m) {
    p = 0; m = l0;
    if (l1 > m) { m = l1; p = 1; }
    if (l2 > m) { m = l2; p = 2; }
}
__device__ __forceinline__ float nll3(float l0, float l1, float l2, int g) {
    float mx = fmaxf(l0, fmaxf(l1, l2));
    float s = __expf(l0 - mx) + __expf(l1 - mx) + __expf(l2 - mx);
    float sel = (g == 0) ? l0 : ((g == 1) ? l1 : l2);
    return mx + __logf(s) - sel;
}
__device__ __forceinline__ void sse4(const float4 &a, const float4 &g, float &s) {
    float d;
    d = a.x - g.x; s = fmaf(d, d, s);  d = a.y - g.y; s = fmaf(d, d, s);
    d = a.z - g.z; s = fmaf(d, d, s);  d = a.w - g.w; s = fmaf(d, d, s);
}
// one row's 12 vel components from row r (p0*) and row r+1 (p1*): velsq + 4 speed norms
__device__ __forceinline__ void vel12(const float4 &p0a, const float4 &p0b, const float4 &p0c,
                                      const float4 &p1a, const float4 &p1b, const float4 &p1c,
                                      float &velsq, float &pen2) {
    float t;
    t = p1a.x - p0a.x; const float q0  = t * t;
    t = p1a.y - p0a.y; const float q1  = t * t;
    t = p1a.z - p0a.z; const float q2  = t * t;
    t = p1a.w - p0a.w; const float q3  = t * t;
    t = p1b.x - p0b.x; const float q4  = t * t;
    t = p1b.y - p0b.y; const float q5  = t * t;
    t = p1b.z - p0b.z; const float q6  = t * t;
    t = p1b.w - p0b.w; const float q7  = t * t;
    t = p1c.x - p0c.x; const float q8  = t * t;
    t = p1c.y - p0c.y; const float q9  = t * t;
    t = p1c.z - p0c.z; const float q10 = t * t;
    t = p1c.w - p0c.w; const float q11 = t * t;
    velsq += (q0 + q1 + q2 + q3) + (q4 + q5 + q6 + q7) + (q8 + q9 + q10 + q11);
    pen2  += pen_term(q0 + q1 + q2) + pen_term(q3 + q4 + q5)
           + pen_term(q6 + q7 + q8) + pen_term(q9 + q10 + q11);
}
__device__ __forceinline__ void acc4(const float4 &r0, const float4 &r1, const float4 &r2, float &accsq) {
    float a;
    a = r2.x - 2.0f * r1.x + r0.x; accsq = fmaf(a, a, accsq);
    a = r2.y - 2.0f * r1.y + r0.y; accsq = fmaf(a, a, accsq);
    a = r2.z - 2.0f * r1.z + r0.z; accsq = fmaf(a, a, accsq);
    a = r2.w - 2.0f * r1.w + r0.w; accsq = fmaf(a, a, accsq);
}

__global__ __launch_bounds__(BLOCK, 4) void combined_loss_main(
    const float4* __restrict__ pred4,
    const float*  __restrict__ ph,
    const float4* __restrict__ gt4,
    const int*    __restrict__ gt_phase,
    double* __restrict__ ws)
{
    __shared__ float s_red[4][6];
    const int tid  = threadIdx.x;
    const int blk  = blockIdx.x;
    const int gtid = blk * BLOCK + tid;

    float sse = 0.f, nllv = 0.f, csum = 0.f, ccnt = 0.f;
    float pen2 = 0.f, velsq = 0.f, accsq = 0.f;

    // ---------------- pred stream: rows (2P, 2P+1) per lane-iter ----------------
    #pragma unroll 1
    for (int u = 0; u < NITER; ++u) {
        const int P = u * NT + gtid;
        const bool tail = ((P + 1) & 4095) == 0;      // t(2P) == 8190: seq end
        const size_t fp = (size_t)P * 6;
        const size_t ep = tail ? fp : fp + 6;         // rows 2P+2,2P+3 (unused if tail)

        const float4 A0 = pred4[fp + 0], A1 = pred4[fp + 1], A2 = pred4[fp + 2];
        const float4 A3 = pred4[fp + 3], A4 = pred4[fp + 4], A5 = pred4[fp + 5];
        const float4 G0 = gt4[fp + 0],   G1 = gt4[fp + 1],   G2 = gt4[fp + 2];
        const float4 G3 = gt4[fp + 3],   G4 = gt4[fp + 4],   G5 = gt4[fp + 5];
        const float4 E0 = pred4[ep + 0], E1 = pred4[ep + 1], E2 = pred4[ep + 2];
        const float4 E3 = pred4[ep + 3], E4 = pred4[ep + 4], E5 = pred4[ep + 5];

        sse4(A0, G0, sse); sse4(A1, G1, sse); sse4(A2, G2, sse);
        sse4(A3, G3, sse); sse4(A4, G4, sse); sse4(A5, G5, sse);

        vel12(A0, A1, A2, A3, A4, A5, velsq, pen2);           // row 2P (always valid)
        if (!tail) {
            vel12(A3, A4, A5, E0, E1, E2, velsq, pen2);       // row 2P+1
            acc4(A0, A3, E0, accsq);                          // acc row 2P
            acc4(A1, A4, E1, accsq);
            acc4(A2, A5, E2, accsq);
            acc4(A3, E0, E3, accsq);                          // acc row 2P+1
            acc4(A4, E1, E4, accsq);
            acc4(A5, E2, E5, accsq);
        }
    }

    // ---------------- phase stream: rows (2L, 2L+1) per lane-iter ----------------
    const float2* ph2  = (const float2*)ph;
    const int2*   gtp2 = (const int2*)gt_phase;
    #pragma unroll 1
    for (int u = 0; u < NITER; ++u) {
        const int L = u * NT + gtid;
        const bool tail = ((L + 1) & 4095) == 0;      // row 2L+1 is seq end
        const size_t pb = (size_t)L * 3;
        const size_t qb = tail ? pb : pb + 3;         // row 2L+2 floats (unused if tail)

        const float2 a  = ph2[pb + 0], b = ph2[pb + 1], c = ph2[pb + 2];
        const float2 e0 = ph2[qb + 0], e1 = ph2[qb + 1];
        const int2   gg = gtp2[L];

        // row 2L = (a.x,a.y,b.x), row 2L+1 = (b.y,c.x,c.y), row 2L+2 = (e0.x,e0.y,e1.x)
        nllv += nll3(a.x, a.y, b.x, gg.x);
        nllv += nll3(b.y, c.x, c.y, gg.y);

        int p0, p1, p2; float m0, m1, m2;
        argmax3(a.x,  a.y,  b.x,  p0, m0);
        argmax3(b.y,  c.x,  c.y,  p1, m1);
        argmax3(e0.x, e0.y, e1.x, p2, m2);

        const int mask0 = (p0 == 0) ? 4 : ((p0 == 1) ? 1 : 3);   // illegal: (0,2),(1,0),(2,0),(2,1)
        if ((mask0 >> p1) & 1) { csum += m1 * m1; ccnt += 1.f; }
        if (!tail) {
            const int mask1 = (p1 == 0) ? 4 : ((p1 == 1) ? 1 : 3);
            if ((mask1 >> p2) & 1) { csum += m2 * m2; ccnt += 1.f; }
        }
    }

    // ---------------- single endgame reduce: 6 chains ----------------
    float vals[6] = { fmaf(12.0f, nllv, sse), csum, ccnt, pen2, velsq, accsq };
    #pragma unroll
    for (int off = 32; off > 0; off >>= 1) {
        #pragma unroll
        for (int q = 0; q < 6; ++q)
            vals[q] += __shfl_down(vals[q], off, 64);
    }
    const int wave = tid >> 6, lane = tid & 63;
    if (lane == 0) {
        #pragma unroll
        for (int q = 0; q < 6; ++q) s_red[wave][q] = vals[q];
    }
    __syncthreads();
    if (tid < 6) {
        const double acc = (double)s_red[0][tid] + (double)s_red[1][tid]
                         + (double)s_red[2][tid] + (double)s_red[3][tid];
        atomicAdd(&ws[(size_t)(blk & (NSLOT - 1)) * 8 + tid], acc);
    }
}

__global__ __launch_bounds__(256) void combined_loss_final(
    const double* __restrict__ ws, float* __restrict__ out)
{
    __shared__ double sred[4][6];
    const int tid = threadIdx.x;
    double v[6];
    #pragma unroll
    for (int q = 0; q < 6; ++q) v[q] = ws[(size_t)tid * 8 + q];
    #pragma unroll
    for (int off = 32; off > 0; off >>= 1) {
        #pragma unroll
        for (int q = 0; q < 6; ++q)
            v[q] += __shfl_down(v[q], off, 64);
    }
    const int wave = tid >> 6, lane = tid & 63;
    if (lane == 0) {
        #pragma unroll
        for (int q = 0; q < 6; ++q) sred[wave][q] = v[q];
    }
    __syncthreads();
    if (tid == 0) {
        double s[6];
        #pragma unroll
        for (int q = 0; q < 6; ++q)
            s[q] = sred[0][q] + sred[1][q] + sred[2][q] + sred[3][q];
        const double robot_phase = s[0] / (double)((size_t)B_DIM * T_DIM * 12);
        const double coher = (s[2] > 0.0) ? (s[1] / fmax(s[2], 1.0)) : 0.0;
        const double speed = 5.0  * (s[3] / (double)((size_t)B_DIM * (T_DIM - 1) * 4));
        const double vel   = 0.05 * (s[4] / (double)((size_t)B_DIM * (T_DIM - 1) * 12));
        const double acc   = 0.01 * (s[5] / (double)((size_t)B_DIM * (T_DIM - 2) * 12));
        out[0] = (float)(robot_phase + 10.0 * coher + speed + vel + acc);
    }
}

extern "C" void kernel_launch(void* const* d_in, const int* in_sizes, int n_in,
                              void* d_out, int out_size, void* d_ws, size_t ws_size,
                              hipStream_t stream)
{
    const float4* pred4      = (const float4*)d_in[0];
    const float*  pred_phase = (const float*)d_in[1];
    const float4* gt4        = (const float4*)d_in[2];
    const int*    gt_phase   = (const int*)d_in[3];
    double* ws  = (double*)d_ws;
    float*  out = (float*)d_out;

    hipMemsetAsync(d_ws, 0, (size_t)NSLOT * 8 * sizeof(double), stream);

    combined_loss_main<<<dim3(GRID), BLOCK, 0, stream>>>(pred4, pred_phase, gt4, gt_phase, ws);
    combined_loss_final<<<1, 256, 0, stream>>>(ws, out);
}